// Round 1
// baseline (344.969 us; speedup 1.0000x reference)
//
#include <hip/hip_runtime.h>
#include <math.h>

// Problem constants: B=8, C=64, H=W=256, M1=M2=16.
#define NIMG 512          // B*C = number of (b,channel) images
#define HW   65536        // 256*256
// Workspace layout (floats): xf_re[131072] xf_im[131072] s_re[131072] s_im[131072] tw_g[8192]
// tw_g layout: [n=256][k=16][2] = (cos, sin)(2*pi*k*n/256)

__global__ __launch_bounds__(256)
void twinit(float* __restrict__ tw_g) {
    int idx = blockIdx.x * 256 + threadIdx.x;   // 0..4095
    int n = idx >> 4, k = idx & 15;
    float s, c;
    sincospif(((k * n) & 255) * (1.0f / 128.0f), &s, &c);  // angle 2*pi*k*n/256, exact reduction
    tw_g[idx * 2]     = c;
    tw_g[idx * 2 + 1] = s;
}

// ---------------- Stage A ----------------
// One block per image (b,i). Phase 1: thread t owns column w=t:
//   C[u,t] = sum_h x[h,t] * e^{-2pi i u h/256}   (16 complex accs in VGPRs)
// Phase 2: transpose via LDS, thread t -> (u=t>>4, v=t&15):
//   Xf[u,v] = sum_w C[u,w] * e^{-2pi i v w/256}
__global__ __launch_bounds__(256, 2)
void stageA(const float* __restrict__ x, const float* __restrict__ tw_g,
            float* __restrict__ xf_re, float* __restrict__ xf_im) {
    __shared__ __attribute__((aligned(16))) float lds[16384];  // 64 KB exactly
    float* tw   = lds;          // [w=256][k=16][2] copy of tw_g (phase-2 per-lane reads)
    float* cbuf = lds + 8192;   // [w=256][u=16][2]
    const int tid = threadIdx.x;
    const int img = blockIdx.x;

    // copy twiddle table to LDS (for phase 2)
    #pragma unroll
    for (int idx = tid; idx < 2048; idx += 256)
        ((float4*)tw)[idx] = ((const float4*)tw_g)[idx];
    __syncthreads();

    const float* xp = x + (size_t)img * HW + tid;
    float cr[16], ci[16];
    #pragma unroll
    for (int u = 0; u < 16; ++u) { cr[u] = 0.0f; ci[u] = 0.0f; }

    const float4* twg4 = (const float4*)tw_g;  // uniform loads -> hopefully s_load
    #pragma unroll 4
    for (int h = 0; h < 256; ++h) {
        float xv = xp[h * 256];               // coalesced dword per lane
        #pragma unroll
        for (int q = 0; q < 8; ++q) {
            float4 e = twg4[h * 8 + q];       // (cos,sin,cos,sin) for u=2q,2q+1 — wave-uniform
            cr[2*q]     += xv * e.x;
            ci[2*q]     -= xv * e.y;
            cr[2*q + 1] += xv * e.z;
            ci[2*q + 1] -= xv * e.w;
        }
    }

    // transpose: cbuf[w][u] = C[u,w]
    #pragma unroll
    for (int u = 0; u < 16; ++u)
        ((float2*)cbuf)[tid * 16 + u] = make_float2(cr[u], ci[u]);
    __syncthreads();

    // phase 2
    const int u = tid >> 4, v = tid & 15;
    float xr = 0.0f, xi = 0.0f;
    #pragma unroll 4
    for (int w = 0; w < 256; ++w) {
        float2 cc = ((const float2*)cbuf)[w * 16 + u];   // 4 distinct addrs/wave, bank-clean
        float ec = tw[w * 32 + v * 2];                   // [w][v] per-lane v: banks 2v, clean
        float es = tw[w * 32 + v * 2 + 1];
        xr += cc.x * ec + cc.y * es;   // (Cr + iCi)(cos - i sin)
        xi += cc.y * ec - cc.x * es;
    }
    xf_re[img * 256 + tid] = xr;
    xf_im[img * 256 + tid] = xi;
}

// ---------------- Stage B ----------------
// S[b,o,u,v] = sum_i Xf[b,i,u,v] * W[i,o,u,v]; thread t = (u*16+v), block = (o,b)
__global__ __launch_bounds__(256)
void stageB(const float* __restrict__ wr, const float* __restrict__ wi,
            const float* __restrict__ xf_re, const float* __restrict__ xf_im,
            float* __restrict__ s_re, float* __restrict__ s_im) {
    const int tid = threadIdx.x;
    const int o = blockIdx.x >> 3;
    const int b = blockIdx.x & 7;
    float sr = 0.0f, si = 0.0f;
    #pragma unroll 4
    for (int i = 0; i < 64; ++i) {
        float wre = wr[((i * 64 + o) << 8) + tid];   // coalesced; shared across b via L2
        float wim = wi[((i * 64 + o) << 8) + tid];
        float xr  = xf_re[((b * 64 + i) << 8) + tid];
        float xi  = xf_im[((b * 64 + i) << 8) + tid];
        sr += xr * wre - xi * wim;
        si += xr * wim + xi * wre;
    }
    s_re[((b * 64 + o) << 8) + tid] = sr;
    s_im[((b * 64 + o) << 8) + tid] = si;
}

// ---------------- Stage C ----------------
// One block per output image (b,o). Thread t owns column w=t.
// Phase 1: T[u,t] = sum_v (c_v/65536) S[u,v] e^{+2pi i v t/256}  (register rotation for e^{ivt})
// Phase 2: out[h,t] = sum_u Re(T[u,t] e^{+2pi i u h/256})        (uniform twiddle loads)
__global__ __launch_bounds__(256, 4)
void stageC(const float* __restrict__ s_re, const float* __restrict__ s_im,
            const float* __restrict__ tw_g, float* __restrict__ out) {
    __shared__ __attribute__((aligned(16))) float sl[512];  // [u][v][2], pre-scaled
    const int tid = threadIdx.x;
    const int img = blockIdx.x;   // b*64 + o

    {
        int v = tid & 15;
        float scale = (v == 0 ? 1.0f : 2.0f) * (1.0f / 65536.0f);
        sl[tid * 2]     = s_re[img * 256 + tid] * scale;
        sl[tid * 2 + 1] = s_im[img * 256 + tid] * scale;
    }
    __syncthreads();

    float tr[16], ti[16];
    #pragma unroll
    for (int u = 0; u < 16; ++u) { tr[u] = 0.0f; ti[u] = 0.0f; }

    // rotation base e^{+2pi i w/256}, w = tid
    float bs, bc;
    sincospif(tid * (1.0f / 128.0f), &bs, &bc);
    float ec = 1.0f, es = 0.0f;   // e^{+i*2pi*v*w/256}, starts at v=0
    for (int v = 0; v < 16; ++v) {
        #pragma unroll
        for (int u = 0; u < 16; ++u) {
            float a = sl[(u * 16 + v) * 2];       // uniform -> LDS broadcast
            float b = sl[(u * 16 + v) * 2 + 1];
            tr[u] += a * ec - b * es;             // (a+ib)(ec+i es)
            ti[u] += a * es + b * ec;
        }
        float nc = ec * bc - es * bs;             // rotate by base
        float ns = ec * bs + es * bc;
        ec = nc; es = ns;
    }

    float* op = out + (size_t)img * HW + tid;
    const float4* twg4 = (const float4*)tw_g;
    #pragma unroll 2
    for (int h = 0; h < 256; ++h) {
        float acc = 0.0f;
        #pragma unroll
        for (int q = 0; q < 8; ++q) {
            float4 e = twg4[h * 8 + q];           // wave-uniform
            acc += tr[2*q]     * e.x - ti[2*q]     * e.y;   // Re(T * e^{+i u h})
            acc += tr[2*q + 1] * e.z - ti[2*q + 1] * e.w;
        }
        op[h * 256] = acc;                        // coalesced store
    }
}

extern "C" void kernel_launch(void* const* d_in, const int* in_sizes, int n_in,
                              void* d_out, int out_size, void* d_ws, size_t ws_size,
                              hipStream_t stream) {
    const float* x  = (const float*)d_in[0];
    const float* wr = (const float*)d_in[1];
    const float* wi = (const float*)d_in[2];
    float* out = (float*)d_out;
    float* ws  = (float*)d_ws;

    float* xf_re = ws;
    float* xf_im = ws + 131072;
    float* s_re  = ws + 262144;
    float* s_im  = ws + 393216;
    float* tw_g  = ws + 524288;   // 8192 floats

    twinit<<<16, 256, 0, stream>>>(tw_g);
    stageA<<<NIMG, 256, 0, stream>>>(x, tw_g, xf_re, xf_im);
    stageB<<<NIMG, 256, 0, stream>>>(wr, wi, xf_re, xf_im, s_re, s_im);
    stageC<<<NIMG, 256, 0, stream>>>(s_re, s_im, tw_g, out);
}

// Round 2
// 283.081 us; speedup vs baseline: 1.2186x; 1.2186x over previous
//
#include <hip/hip_runtime.h>
#include <math.h>

// Problem constants: B=8, C=64, H=W=256, M1=M2=16.
#define NIMG 512          // B*C
#define HW   65536        // 256*256
// Workspace (floats): xf_re[131072] xf_im[131072] s_re[131072] s_im[131072] tw_g[2048]
// tw_g layout: [n=64][k=16][2] = (cos, sin)(2*pi*k*n/256)  — radix-4 base table, 8 KB

__global__ __launch_bounds__(256)
void twinit(float* __restrict__ tw_g) {
    int idx = blockIdx.x * 256 + threadIdx.x;   // 0..1023
    int n = idx >> 4, k = idx & 15;
    float s, c;
    sincospif(((k * n) & 255) * (1.0f / 128.0f), &s, &c);  // 2*pi*k*n/256, exact reduction
    tw_g[idx * 2]     = c;
    tw_g[idx * 2 + 1] = s;
}

// ---------------- Stage A ----------------
// One block per image (b,i). Radix-4 over h and over w.
// Phase 1 (thread t = column w): C[u,t] = sum_h x[h,t] e^{-2pi i u h/256}
//   rows {hb, hb+64, hb+128, hb+192} share twiddle tw[u,hb] with factors (-i)^u.
// Phase 2 (thread t -> u=t>>4, v=t&15): Xf[u,v] = sum_w C[u,w] e^{-2pi i v w/256}
__global__ __launch_bounds__(256, 4)
void stageA(const float* __restrict__ x, const float* __restrict__ tw_g,
            float* __restrict__ xf_re, float* __restrict__ xf_im) {
    __shared__ __attribute__((aligned(16))) float tw[2048];   // [n=64][k=16][2], 8 KB
    __shared__ __attribute__((aligned(16))) float cbuf[8192]; // [u=16][w=256][2], 32 KB
    const int tid = threadIdx.x;
    const int img = blockIdx.x;

    ((float4*)tw)[tid]       = ((const float4*)tw_g)[tid];
    ((float4*)tw)[tid + 256] = ((const float4*)tw_g)[tid + 256];
    __syncthreads();

    const float* xp = x + (size_t)img * HW + tid;
    float cr[16], ci[16];
    #pragma unroll
    for (int u = 0; u < 16; ++u) { cr[u] = 0.0f; ci[u] = 0.0f; }

    const float4* tw4 = (const float4*)tw;
    #pragma unroll 2
    for (int hb = 0; hb < 64; ++hb) {
        float a = xp[hb * 256];               // 4 coalesced dword loads
        float b = xp[(hb + 64) * 256];
        float c = xp[(hb + 128) * 256];
        float d = xp[(hb + 192) * 256];
        float p = a + c, m = a - c, q = b + d, r = b - d;
        float s0 = p + q, s2 = p - q;         // even-u real inputs
        #pragma unroll
        for (int qq = 0; qq < 8; ++qq) {      // u = 2qq (even), 2qq+1 (odd)
            float4 e = tw4[hb * 8 + qq];      // uniform -> LDS broadcast b128
            float se = (qq & 1) ? s2 : s0;    // even u: u%4==0 -> s0, ==2 -> s2
            float si = (qq & 1) ? r : -r;     // odd u: u%4==1 -> m-ir, ==3 -> m+ir
            cr[2*qq]     += se * e.x;         // s_real * (c - i s)
            ci[2*qq]     -= se * e.y;
            cr[2*qq + 1] += m  * e.z + si * e.w;   // (m + i si)(c - i s)
            ci[2*qq + 1] += si * e.z - m  * e.w;
        }
    }

    float2* cb = (float2*)cbuf;               // [u*256 + w]: lane-stride 8B, bank-clean
    #pragma unroll
    for (int u = 0; u < 16; ++u)
        cb[u * 256 + tid] = make_float2(cr[u], ci[u]);
    __syncthreads();

    const int u = tid >> 4, v = tid & 15;
    const bool odd = (v & 1) != 0;
    const float t = (v & 2) ? -1.0f : 1.0f;
    const float2* twc = (const float2*)tw;
    float xr = 0.0f, xi = 0.0f;
    #pragma unroll 2
    for (int wb = 0; wb < 64; ++wb) {
        float2 Ca = cb[u * 256 + wb];         // 4-addr broadcasts
        float2 Cb = cb[u * 256 + wb + 64];
        float2 Cc = cb[u * 256 + wb + 128];
        float2 Cd = cb[u * 256 + wb + 192];
        float pr = Ca.x + Cc.x, pi_ = Ca.y + Cc.y;
        float mr = Ca.x - Cc.x, mi  = Ca.y - Cc.y;
        float qr = Cb.x + Cd.x, qi  = Cb.y + Cd.y;
        float rr = Cb.x - Cd.x, ri  = Cb.y - Cd.y;
        float X1 = odd ? mr : pr;             // class select (cndmask, no divergence)
        float X2 = odd ? ri : qr;
        float Y1 = odd ? mi : pi_;
        float Y2 = odd ? -rr : qi;
        float sr = X1 + t * X2;
        float si = Y1 + t * Y2;
        float2 e = twc[wb * 16 + v];          // per-lane v, same-addr broadcast x4
        xr += sr * e.x + si * e.y;            // s * (c - i s)
        xi += si * e.x - sr * e.y;
    }
    xf_re[img * 256 + tid] = xr;
    xf_im[img * 256 + tid] = xi;
}

// ---------------- Stage B ----------------
__global__ __launch_bounds__(256)
void stageB(const float* __restrict__ wr, const float* __restrict__ wi,
            const float* __restrict__ xf_re, const float* __restrict__ xf_im,
            float* __restrict__ s_re, float* __restrict__ s_im) {
    const int tid = threadIdx.x;
    const int o = blockIdx.x >> 3;
    const int b = blockIdx.x & 7;
    float sr = 0.0f, si = 0.0f;
    #pragma unroll 4
    for (int i = 0; i < 64; ++i) {
        float wre = wr[((i * 64 + o) << 8) + tid];
        float wim = wi[((i * 64 + o) << 8) + tid];
        float xr  = xf_re[((b * 64 + i) << 8) + tid];
        float xi  = xf_im[((b * 64 + i) << 8) + tid];
        sr += xr * wre - xi * wim;
        si += xr * wim + xi * wre;
    }
    s_re[((b * 64 + o) << 8) + tid] = sr;
    s_im[((b * 64 + o) << 8) + tid] = si;
}

// ---------------- Stage C ----------------
// One block per output image (b,o). Thread t = column w.
// Phase 1: T[u,t] = sum_v (c_v/65536) S[u,v] e^{+2pi i v t/256}  (register rotation, 16 steps)
// Phase 2 (radix-4 over h): out[h,t] = sum_u Re(T_u e^{+2pi i u h/256}),
//   outputs {hb, hb+64, hb+128, hb+192} share twiddles with factors (i)^u.
__global__ __launch_bounds__(256, 4)
void stageC(const float* __restrict__ s_re, const float* __restrict__ s_im,
            const float* __restrict__ tw_g, float* __restrict__ out) {
    __shared__ __attribute__((aligned(16))) float tw[2048];  // 8 KB
    __shared__ __attribute__((aligned(16))) float sl[512];   // [u][v][2], pre-scaled
    const int tid = threadIdx.x;
    const int img = blockIdx.x;   // b*64 + o

    ((float4*)tw)[tid]       = ((const float4*)tw_g)[tid];
    ((float4*)tw)[tid + 256] = ((const float4*)tw_g)[tid + 256];
    {
        int v = tid & 15;
        float scale = (v == 0 ? 1.0f : 2.0f) * (1.0f / 65536.0f);
        sl[tid * 2]     = s_re[img * 256 + tid] * scale;
        sl[tid * 2 + 1] = s_im[img * 256 + tid] * scale;
    }
    __syncthreads();

    float tr[16], ti[16];
    #pragma unroll
    for (int u = 0; u < 16; ++u) { tr[u] = 0.0f; ti[u] = 0.0f; }

    float bs, bc;
    sincospif(tid * (1.0f / 128.0f), &bs, &bc);   // e^{+2pi i w/256}
    float ec = 1.0f, es = 0.0f;
    for (int v = 0; v < 16; ++v) {
        #pragma unroll
        for (int u = 0; u < 16; ++u) {
            float a = sl[(u * 16 + v) * 2];       // uniform -> broadcast
            float b = sl[(u * 16 + v) * 2 + 1];
            tr[u] += a * ec - b * es;
            ti[u] += a * es + b * ec;
        }
        float nc = ec * bc - es * bs;
        float ns = ec * bs + es * bc;
        ec = nc; es = ns;
    }

    float* op = out + (size_t)img * HW + tid;
    const float4* tw4 = (const float4*)tw;
    #pragma unroll 2
    for (int hb = 0; hb < 64; ++hb) {
        float o0 = 0.f, o1 = 0.f, o2 = 0.f, o3 = 0.f;
        #pragma unroll
        for (int qq = 0; qq < 8; ++qq) {          // u = 2qq, 2qq+1
            float4 e = tw4[hb * 8 + qq];          // uniform broadcast
            float pre = tr[2*qq]   * e.x - ti[2*qq]   * e.y;   // Re(T_even e^{+iuh})
            float pro = tr[2*qq+1] * e.z - ti[2*qq+1] * e.w;   // Re(T_odd  e^{+iuh})
            float pio = tr[2*qq+1] * e.w + ti[2*qq+1] * e.z;   // Im(T_odd  e^{+iuh})
            o0 += pre + pro;
            o2 += pre - pro;
            float g1 = pre - pio, g3 = pre + pio;
            if (qq & 1) { o1 -= g1; o3 -= g3; }   // static sign after unroll
            else        { o1 += g1; o3 += g3; }
        }
        op[hb * 256]         = o0;                // 4 coalesced stores
        op[(hb + 64) * 256]  = o1;
        op[(hb + 128) * 256] = o2;
        op[(hb + 192) * 256] = o3;
    }
}

extern "C" void kernel_launch(void* const* d_in, const int* in_sizes, int n_in,
                              void* d_out, int out_size, void* d_ws, size_t ws_size,
                              hipStream_t stream) {
    const float* x  = (const float*)d_in[0];
    const float* wr = (const float*)d_in[1];
    const float* wi = (const float*)d_in[2];
    float* out = (float*)d_out;
    float* ws  = (float*)d_ws;

    float* xf_re = ws;
    float* xf_im = ws + 131072;
    float* s_re  = ws + 262144;
    float* s_im  = ws + 393216;
    float* tw_g  = ws + 524288;   // 2048 floats

    twinit<<<4, 256, 0, stream>>>(tw_g);
    stageA<<<NIMG, 256, 0, stream>>>(x, tw_g, xf_re, xf_im);
    stageB<<<NIMG, 256, 0, stream>>>(wr, wi, xf_re, xf_im, s_re, s_im);
    stageC<<<NIMG, 256, 0, stream>>>(s_re, s_im, tw_g, out);
}